// Round 7
// baseline (718.687 us; speedup 1.0000x reference)
//
#include <hip/hip_runtime.h>

typedef unsigned int uint;
typedef unsigned short ushort;
typedef __attribute__((ext_vector_type(8))) short bhalf8;
typedef __attribute__((ext_vector_type(4))) float floatx4;

#define D_IN 256
#define NUNIT 256     // live hidden units (256:512 dead: h_new[:,256:] never read)
#define GN 1024       // gates N = 4 gates x 256 units
#define NSUP 512
#define BATCH_N 32768
#define LDA_A 768     // A_cat: [h_a(0:256) | r(256:512) | h_b(512:768)]

__device__ __forceinline__ ushort f2b(float f){
  union { float f; uint u; } x; x.f = f;
  uint r = (x.u + 0x7fffu + ((x.u >> 16) & 1u)) >> 16;
  return (ushort)r;
}
__device__ __forceinline__ float b2f(ushort u){
  union { uint u; float f; } x; x.u = ((uint)u) << 16;
  return x.f;
}
__device__ __forceinline__ float sigmf(float x){ return 1.0f / (1.0f + __expf(-x)); }
__device__ __forceinline__ float tanhfast(float x){ return 1.0f - 2.0f / (1.0f + __expf(2.0f * x)); }

// ---------------------------------------------------------------------------
// global->LDS staging of a 128x64 bf16 tile with SOURCE PRE-SWIZZLE (m173):
// LDS linear; lane fetches global octet (lane&7)^(lane>>3) so
// LDS[R][o] = G[R][o ^ (R&7)]; reads apply the same XOR (frag_ld).
// Verified round 5: bank conflicts 3.8e7 -> 0.
// ---------------------------------------------------------------------------
__device__ __forceinline__ void stage_swz(
    ushort* lds, const ushort* __restrict__ g, int ld, int row0, int k0,
    int wave, int lane)
{
  const int rsub = lane >> 3;
  const int oct  = (lane & 7) ^ rsub;
  #pragma unroll
  for (int q = 0; q < 4; q++) {
    const ushort* gp = g + (long)(row0 + wave * 32 + q * 8 + rsub) * ld
                         + k0 + (oct << 3);
    ushort* lp = lds + (wave * 32 + q * 8) * 64;
    __builtin_amdgcn_global_load_lds(
        (const __attribute__((address_space(1))) void*)gp,
        (__attribute__((address_space(3))) void*)lp, 16, 0, 0);
  }
}

__device__ __forceinline__ bhalf8 frag_ld(const ushort* lds, int R, int O, int sx)
{
  return *reinterpret_cast<const bhalf8*>(&lds[R * 64 + (((O ^ sx) & 7) << 3)]);
}

// ---------------------------------------------------------------------------
// Gq = q @ Wq^T + bias (K=256, N=1024, permuted cols) -> packed bf16 uint2
// {i|f, g|o} per (row,unit). Epilogue also runs step-0 pointwise.
// 2-phase prefetch pipeline + LDS-coalesced writeout.
// ---------------------------------------------------------------------------
__global__ __launch_bounds__(256) void gemm_gq_fused(
    const ushort* __restrict__ Qb,     // [32768,256] bf16
    const ushort* __restrict__ Wq,     // permuted [1024,256]
    const float4* __restrict__ biasp,  // [256] (b_i,b_f,b_g,b_o)
    uint2* __restrict__ Gq,            // [32768*256]
    float* __restrict__ cbuf,          // [32768,256]
    const float* __restrict__ query,   // fp32
    ushort* __restrict__ Hhi,          // Abuf + 0 (stride LDA_A)
    ushort* __restrict__ Hlo)          // [32768,256]
{
  __shared__ ushort SM[2][2][8192];   // [buf][A/B][128*64] = 64 KB

  const int tid  = threadIdx.x;
  const int lane = tid & 63;
  const int wave = tid >> 6;
  const int wr = (wave >> 1) * 64;
  const int wc = (wave & 1) * 64;
  const int wg = (blockIdx.x & 7) * (gridDim.x >> 3) + (blockIdx.x >> 3);
  const int bm = wg >> 3;             // GN/128 = 8 col-blocks
  const int bn = wg & 7;
  const int rowA0 = bm * 128;
  const int colB0 = bn * 128;

  floatx4 acc[4][4];
  #pragma unroll
  for (int m = 0; m < 4; m++)
    #pragma unroll
    for (int n = 0; n < 4; n++)
      acc[m][n] = (floatx4){0.f, 0.f, 0.f, 0.f};

  const int lr = lane & 15;
  const int lg = lane >> 4;
  const int sx = lane & 7;
  const int NT = 4;                   // K=256

  stage_swz(SM[0][0], Qb, 256, rowA0, 0, wave, lane);
  stage_swz(SM[0][1], Wq, 256, colB0, 0, wave, lane);
  __syncthreads();
  for (int t = 0; t < NT; t++) {
    const int cur = t & 1;
    if (t + 1 < NT) {
      stage_swz(SM[cur ^ 1][0], Qb, 256, rowA0, (t + 1) * 64, wave, lane);
      stage_swz(SM[cur ^ 1][1], Wq, 256, colB0, (t + 1) * 64, wave, lane);
    }
    const ushort* As = SM[cur][0];
    const ushort* Bs = SM[cur][1];
    #pragma unroll
    for (int ks = 0; ks < 2; ks++) {
      bhalf8 af[4], bfr[4];
      #pragma unroll
      for (int m = 0; m < 4; m++)
        af[m] = frag_ld(As, wr + m * 16 + lr, ks * 4 + lg, sx);
      #pragma unroll
      for (int n = 0; n < 4; n++)
        bfr[n] = frag_ld(Bs, wc + n * 16 + lr, ks * 4 + lg, sx);
      #pragma unroll
      for (int m = 0; m < 4; m++)
        #pragma unroll
        for (int n = 0; n < 4; n++)
          acc[m][n] = __builtin_amdgcn_mfma_f32_16x16x32_bf16(af[m], bfr[n], acc[m][n], 0, 0, 0);
    }
    __syncthreads();
  }

  // ---- epilogue: pointwise into LDS, then coalesced writeout ----
  uint2*  egq = (uint2*)&SM[0][0][0];                 // [128][32] uint2 = 32 KB
  ushort* ehi = (ushort*)&SM[1][0][0];                // [128][32] = 8 KB
  ushort* elo = ehi + 128 * 32;                       // 8 KB
  float*  ec  = (float*)&SM[1][1][0];                 // [128][32] f32 = 16 KB

  const int u_loc = (wave & 1) * 16 + lr;             // 0..31
  const int u     = bn * 32 + u_loc;
  const float4 b4 = biasp[u];
  #pragma unroll
  for (int m = 0; m < 4; m++) {
    #pragma unroll
    for (int rr = 0; rr < 4; rr++) {
      const int  rloc = wr + m * 16 + lg * 4 + rr;
      const long row  = rowA0 + rloc;
      float pi = acc[m][0][rr] + b4.x;
      float pf = acc[m][1][rr] + b4.y;
      float pg = acc[m][2][rr] + b4.z;
      float po = acc[m][3][rr] + b4.w;
      uint2 pk;
      pk.x = (uint)f2b(pi) | ((uint)f2b(pf) << 16);
      pk.y = (uint)f2b(pg) | ((uint)f2b(po) << 16);
      egq[rloc * 32 + u_loc] = pk;
      float cn = sigmf(pi) * tanhfast(pg);
      ec[rloc * 32 + u_loc] = cn;
      float h = query[row * D_IN + u] + sigmf(po) * tanhfast(cn);
      ushort hh = f2b(h);
      ehi[rloc * 32 + u_loc] = hh;
      elo[rloc * 32 + u_loc] = f2b(h - b2f(hh));
    }
  }
  __syncthreads();
  const int u0 = bn * 32;
  for (int i = tid; i < 512; i += 256) {              // hi / lo: [128][32]u16
    int row = i >> 2, part = i & 3;
    *(uint4*)(Hhi + (long)(rowA0 + row) * LDA_A + u0 + part * 8) = ((const uint4*)ehi)[i];
    *(uint4*)(Hlo + (long)(rowA0 + row) * D_IN + u0 + part * 8) = ((const uint4*)elo)[i];
  }
  for (int i = tid; i < 1024; i += 256) {             // c: [128][32]f32
    int row = i >> 3, part = i & 7;
    *(uint4*)(cbuf + (long)(rowA0 + row) * NUNIT + u0 + part * 4) = ((const uint4*)ec)[i];
  }
  for (int i = tid; i < 2048; i += 256) {             // Gq: [128][32]uint2
    int row = i >> 4, part = i & 15;
    *(uint4*)((char*)(Gq + (long)(rowA0 + row) * NUNIT + u0) + part * 16) = ((const uint4*)egq)[i];
  }
}

// ---------------------------------------------------------------------------
// Steps 1-3: gates = A[:, aoff:aoff+512] @ Whh'^T (K=512, N=1024) + Gq;
// fused LSTM pointwise. 2-phase prefetch + LDS-coalesced writeout.
// ---------------------------------------------------------------------------
__global__ __launch_bounds__(256) void gemm_gates_fused(
    const ushort* __restrict__ A,      // Abuf + aoff (lda LDA_A)
    const ushort* __restrict__ W,      // permuted [1024,512]
    const uint2* __restrict__ Gq,      // packed q-contribution (incl bias)
    float* __restrict__ cbuf,
    const float* __restrict__ query,
    ushort* __restrict__ Hhi,          // A_cat h-out slot (stride LDA_A)
    ushort* __restrict__ Hlo)
{
  __shared__ ushort SM[2][2][8192];

  const int tid  = threadIdx.x;
  const int lane = tid & 63;
  const int wave = tid >> 6;
  const int wr = (wave >> 1) * 64;
  const int wc = (wave & 1) * 64;
  const int wg = (blockIdx.x & 7) * (gridDim.x >> 3) + (blockIdx.x >> 3);
  const int bm = wg >> 3;
  const int bn = wg & 7;
  const int rowA0 = bm * 128;
  const int colB0 = bn * 128;

  floatx4 acc[4][4];
  #pragma unroll
  for (int m = 0; m < 4; m++)
    #pragma unroll
    for (int n = 0; n < 4; n++)
      acc[m][n] = (floatx4){0.f, 0.f, 0.f, 0.f};

  const int lr = lane & 15;
  const int lg = lane >> 4;
  const int sx = lane & 7;
  const int NT = 8;                   // K=512

  stage_swz(SM[0][0], A, LDA_A, rowA0, 0, wave, lane);
  stage_swz(SM[0][1], W, 512,   colB0, 0, wave, lane);
  __syncthreads();
  for (int t = 0; t < NT; t++) {
    const int cur = t & 1;
    if (t + 1 < NT) {
      stage_swz(SM[cur ^ 1][0], A, LDA_A, rowA0, (t + 1) * 64, wave, lane);
      stage_swz(SM[cur ^ 1][1], W, 512,   colB0, (t + 1) * 64, wave, lane);
    }
    const ushort* As = SM[cur][0];
    const ushort* Bs = SM[cur][1];
    #pragma unroll
    for (int ks = 0; ks < 2; ks++) {
      bhalf8 af[4], bfr[4];
      #pragma unroll
      for (int m = 0; m < 4; m++)
        af[m] = frag_ld(As, wr + m * 16 + lr, ks * 4 + lg, sx);
      #pragma unroll
      for (int n = 0; n < 4; n++)
        bfr[n] = frag_ld(Bs, wc + n * 16 + lr, ks * 4 + lg, sx);
      #pragma unroll
      for (int m = 0; m < 4; m++)
        #pragma unroll
        for (int n = 0; n < 4; n++)
          acc[m][n] = __builtin_amdgcn_mfma_f32_16x16x32_bf16(af[m], bfr[n], acc[m][n], 0, 0, 0);
    }
    __syncthreads();
  }

  // ---- epilogue ----
  ushort* ehi = (ushort*)&SM[0][0][0];                // [128][32] = 8 KB
  ushort* elo = ehi + 128 * 32;                       // 8 KB
  float*  ec  = (float*)&SM[0][1][0];                 // 16 KB

  const int u_loc = (wave & 1) * 16 + lr;
  const int u     = bn * 32 + u_loc;
  #pragma unroll
  for (int m = 0; m < 4; m++) {
    #pragma unroll
    for (int rr = 0; rr < 4; rr++) {
      const int  rloc = wr + m * 16 + lg * 4 + rr;
      const long row  = rowA0 + rloc;
      uint2 pk = Gq[row * NUNIT + u];
      float pi = acc[m][0][rr] + b2f((ushort)(pk.x & 0xffff));
      float pf = acc[m][1][rr] + b2f((ushort)(pk.x >> 16));
      float pg = acc[m][2][rr] + b2f((ushort)(pk.y & 0xffff));
      float po = acc[m][3][rr] + b2f((ushort)(pk.y >> 16));
      float cn = sigmf(pf) * cbuf[row * NUNIT + u] + sigmf(pi) * tanhfast(pg);
      ec[rloc * 32 + u_loc] = cn;
      float h = query[row * D_IN + u] + sigmf(po) * tanhfast(cn);
      ushort hh = f2b(h);
      ehi[rloc * 32 + u_loc] = hh;
      elo[rloc * 32 + u_loc] = f2b(h - b2f(hh));
    }
  }
  __syncthreads();
  const int u0 = bn * 32;
  for (int i = tid; i < 512; i += 256) {
    int row = i >> 2, part = i & 3;
    *(uint4*)(Hhi + (long)(rowA0 + row) * LDA_A + u0 + part * 8) = ((const uint4*)ehi)[i];
    *(uint4*)(Hlo + (long)(rowA0 + row) * D_IN + u0 + part * 8) = ((const uint4*)elo)[i];
  }
  for (int i = tid; i < 1024; i += 256) {
    int row = i >> 3, part = i & 7;
    *(uint4*)(cbuf + (long)(rowA0 + row) * NUNIT + u0 + part * 4) = ((const uint4*)ec)[i];
  }
}

// ---------------------------------------------------------------------------
// Split-precision scores GEMM: C = (Ahi+Alo)@(Bhi+Blo)^T, lo*lo dropped.
// Ahi from A_cat h-slot (lda 768). K=256. C fp32 [32768,512]. (unchanged)
// ---------------------------------------------------------------------------
__global__ __launch_bounds__(256) void gemm_scores(
    const ushort* __restrict__ Ahi,
    const ushort* __restrict__ Alo,
    const ushort* __restrict__ Bhi, const ushort* __restrict__ Blo,
    float* __restrict__ C)
{
  __shared__ ushort AsH[128 * 64];
  __shared__ ushort AsL[128 * 64];
  __shared__ ushort BsH[128 * 64];
  __shared__ ushort BsL[128 * 64];

  const int tid  = threadIdx.x;
  const int lane = tid & 63;
  const int wave = tid >> 6;
  const int wr = (wave >> 1) * 64;
  const int wc = (wave & 1) * 64;
  const int wg = (blockIdx.x & 7) * (gridDim.x >> 3) + (blockIdx.x >> 3);
  const int bm = wg >> 2;      // NSUP/128 = 4
  const int bn = wg & 3;
  const int rowA0 = bm * 128;
  const int rowB0 = bn * 128;

  floatx4 acc[4][4];
  #pragma unroll
  for (int m = 0; m < 4; m++)
    #pragma unroll
    for (int n = 0; n < 4; n++)
      acc[m][n] = (floatx4){0.f, 0.f, 0.f, 0.f};

  const int lr = lane & 15;
  const int lg = lane >> 4;
  const int sx = lane & 7;

  for (int k0 = 0; k0 < D_IN; k0 += 64) {
    stage_swz(AsH, Ahi, LDA_A, rowA0, k0, wave, lane);
    stage_swz(AsL, Alo, D_IN,  rowA0, k0, wave, lane);
    stage_swz(BsH, Bhi, D_IN,  rowB0, k0, wave, lane);
    stage_swz(BsL, Blo, D_IN,  rowB0, k0, wave, lane);
    __syncthreads();
    #pragma unroll
    for (int ks = 0; ks < 2; ks++) {
      bhalf8 afh[4], afl[4], bfh[4], bfl[4];
      #pragma unroll
      for (int m = 0; m < 4; m++) {
        afh[m] = frag_ld(AsH, wr + m * 16 + lr, ks * 4 + lg, sx);
        afl[m] = frag_ld(AsL, wr + m * 16 + lr, ks * 4 + lg, sx);
      }
      #pragma unroll
      for (int n = 0; n < 4; n++) {
        bfh[n] = frag_ld(BsH, wc + n * 16 + lr, ks * 4 + lg, sx);
        bfl[n] = frag_ld(BsL, wc + n * 16 + lr, ks * 4 + lg, sx);
      }
      #pragma unroll
      for (int m = 0; m < 4; m++)
        #pragma unroll
        for (int n = 0; n < 4; n++) {
          acc[m][n] = __builtin_amdgcn_mfma_f32_16x16x32_bf16(afl[m], bfh[n], acc[m][n], 0, 0, 0);
          acc[m][n] = __builtin_amdgcn_mfma_f32_16x16x32_bf16(afh[m], bfl[n], acc[m][n], 0, 0, 0);
          acc[m][n] = __builtin_amdgcn_mfma_f32_16x16x32_bf16(afh[m], bfh[n], acc[m][n], 0, 0, 0);
        }
    }
    __syncthreads();
  }

  #pragma unroll
  for (int m = 0; m < 4; m++)
    #pragma unroll
    for (int n = 0; n < 4; n++)
      #pragma unroll
      for (int r = 0; r < 4; r++) {
        int row = rowA0 + wr + m * 16 + lg * 4 + r;
        int col = rowB0 + wc + n * 16 + lr;
        C[(long)row * NSUP + col] = acc[m][n][r];
      }
}

// ---------------------------------------------------------------------------
// PV GEMM: r = attn @ STb^T (K=512), bf16 out into A_cat r-slot (ldc 768).
// 2-phase prefetch + LDS-coalesced writeout.
// ---------------------------------------------------------------------------
__global__ __launch_bounds__(256) void gemm_pv(
    const ushort* __restrict__ A,      // attn [32768,512]
    const ushort* __restrict__ B,      // STb [256,512]
    ushort* __restrict__ Cv)           // Abuf + 256
{
  __shared__ ushort SM[2][2][8192];

  const int tid  = threadIdx.x;
  const int lane = tid & 63;
  const int wave = tid >> 6;
  const int wr = (wave >> 1) * 64;
  const int wc = (wave & 1) * 64;
  const int wg = (blockIdx.x & 7) * (gridDim.x >> 3) + (blockIdx.x >> 3);
  const int bm = wg >> 1;             // D_IN/128 = 2
  const int bn = wg & 1;
  const int rowA0 = bm * 128;
  const int rowB0 = bn * 128;

  floatx4 acc[4][4];
  #pragma unroll
  for (int m = 0; m < 4; m++)
    #pragma unroll
    for (int n = 0; n < 4; n++)
      acc[m][n] = (floatx4){0.f, 0.f, 0.f, 0.f};

  const int lr = lane & 15;
  const int lg = lane >> 4;
  const int sx = lane & 7;
  const int NT = 8;                   // K=512

  stage_swz(SM[0][0], A, NSUP, rowA0, 0, wave, lane);
  stage_swz(SM[0][1], B, NSUP, rowB0, 0, wave, lane);
  __syncthreads();
  for (int t = 0; t < NT; t++) {
    const int cur = t & 1;
    if (t + 1 < NT) {
      stage_swz(SM[cur ^ 1][0], A, NSUP, rowA0, (t + 1) * 64, wave, lane);
      stage_swz(SM[cur ^ 1][1], B, NSUP, rowB0, (t + 1) * 64, wave, lane);
    }
    const ushort* As = SM[cur][0];
    const ushort* Bs = SM[cur][1];
    #pragma unroll
    for (int ks = 0; ks < 2; ks++) {
      bhalf8 af[4], bfr[4];
      #pragma unroll
      for (int m = 0; m < 4; m++)
        af[m] = frag_ld(As, wr + m * 16 + lr, ks * 4 + lg, sx);
      #pragma unroll
      for (int n = 0; n < 4; n++)
        bfr[n] = frag_ld(Bs, wc + n * 16 + lr, ks * 4 + lg, sx);
      #pragma unroll
      for (int m = 0; m < 4; m++)
        #pragma unroll
        for (int n = 0; n < 4; n++)
          acc[m][n] = __builtin_amdgcn_mfma_f32_16x16x32_bf16(af[m], bfr[n], acc[m][n], 0, 0, 0);
    }
    __syncthreads();
  }

  // epilogue: r tile [128 rows][128 cols] bf16 via LDS, coalesced writeout
  ushort* elr = (ushort*)&SM[0][0][0];                // 32 KB
  #pragma unroll
  for (int m = 0; m < 4; m++)
    #pragma unroll
    for (int n = 0; n < 4; n++)
      #pragma unroll
      for (int r = 0; r < 4; r++) {
        int rloc = wr + m * 16 + lg * 4 + r;
        int cloc = wc + n * 16 + lr;
        elr[rloc * 128 + cloc] = f2b(acc[m][n][r]);
      }
  __syncthreads();
  for (int i = tid; i < 2048; i += 256) {
    int row = i >> 4, part = i & 15;
    *(uint4*)(Cv + (long)(rowA0 + row) * LDA_A + rowB0 + part * 8) = ((const uint4*)elr)[i];
  }
}

// ---------------------------------------------------------------------------
// Build permuted live-unit weights + bias + S hi/lo + S^T. (unchanged)
// ---------------------------------------------------------------------------
__global__ __launch_bounds__(256) void k_build(
    const float* __restrict__ Wih, const float* __restrict__ Whh,
    const float* __restrict__ bih, const float* __restrict__ bhh,
    const float* __restrict__ S,
    ushort* __restrict__ We, ushort* __restrict__ Wo, ushort* __restrict__ Wq,
    float4* __restrict__ biasp,
    ushort* __restrict__ Shi, ushort* __restrict__ Slo,
    ushort* __restrict__ STb)
{
  int t = blockIdx.x * 256 + threadIdx.x;
  if (t < GN * 512) {
    int c = t >> 9, k = t & 511;
    int unit = (c >> 6) * 16 + (c & 15);
    int gate = (c >> 4) & 3;
    long srow = (long)(gate * 512 + unit);
    We[(long)c * 512 + k] = f2b(Whh[srow * 512 + k]);
    int ko = (k < 256) ? (256 + k) : (k - 256);
    Wo[(long)c * 512 + k] = f2b(Whh[srow * 512 + ko]);
    if (k < 256) Wq[(long)c * 256 + k] = f2b(Wih[srow * 256 + k]);
  }
  if (t < NUNIT) {
    biasp[t] = make_float4(bih[t] + bhh[t],
                           bih[512 + t] + bhh[512 + t],
                           bih[1024 + t] + bhh[1024 + t],
                           bih[1536 + t] + bhh[1536 + t]);
  }
  if (t < NSUP * D_IN) {
    float v = S[t];
    ushort hv = f2b(v);
    Shi[t] = hv;
    Slo[t] = f2b(v - b2f(hv));
    int s = t >> 8, d = t & 255;
    STb[(long)d * NSUP + s] = hv;
  }
}

// bf16 copy of query for the Gq GEMM.
__global__ __launch_bounds__(256) void k_initq(
    const float* __restrict__ query, ushort* __restrict__ Qb)
{
  long t = (long)blockIdx.x * 256 + threadIdx.x;
  Qb[t] = f2b(query[t]);
}

// Row softmax over 512 cols, fp32 in, bf16 out. 1 wave / row. (unchanged)
__global__ __launch_bounds__(256) void k_softmax(
    const float* __restrict__ sc, ushort* __restrict__ attn)
{
  int row  = blockIdx.x * 4 + (threadIdx.x >> 6);
  int lane = threadIdx.x & 63;
  const float4* sp = reinterpret_cast<const float4*>(sc + (long)row * NSUP);
  float4 v0 = sp[lane];
  float4 v1 = sp[64 + lane];
  float m = fmaxf(fmaxf(fmaxf(v0.x, v0.y), fmaxf(v0.z, v0.w)),
                  fmaxf(fmaxf(v1.x, v1.y), fmaxf(v1.z, v1.w)));
  #pragma unroll
  for (int off = 32; off >= 1; off >>= 1) m = fmaxf(m, __shfl_xor(m, off));
  float e0 = __expf(v0.x - m), e1 = __expf(v0.y - m), e2 = __expf(v0.z - m), e3 = __expf(v0.w - m);
  float e4 = __expf(v1.x - m), e5 = __expf(v1.y - m), e6 = __expf(v1.z - m), e7 = __expf(v1.w - m);
  float s = e0 + e1 + e2 + e3 + e4 + e5 + e6 + e7;
  #pragma unroll
  for (int off = 32; off >= 1; off >>= 1) s += __shfl_xor(s, off);
  float inv = 1.0f / s;
  uint2 p0, p1;
  p0.x = (uint)f2b(e0 * inv) | ((uint)f2b(e1 * inv) << 16);
  p0.y = (uint)f2b(e2 * inv) | ((uint)f2b(e3 * inv) << 16);
  p1.x = (uint)f2b(e4 * inv) | ((uint)f2b(e5 * inv) << 16);
  p1.y = (uint)f2b(e6 * inv) | ((uint)f2b(e7 * inv) << 16);
  uint2* ap = reinterpret_cast<uint2*>(attn + (long)row * NSUP);
  ap[lane] = p0;
  ap[64 + lane] = p1;
}

// ---------------------------------------------------------------------------
extern "C" void kernel_launch(void* const* d_in, const int* in_sizes, int n_in,
                              void* d_out, int out_size, void* d_ws, size_t ws_size,
                              hipStream_t stream)
{
  const float* support_mean = (const float*)d_in[0];
  const float* query_mean   = (const float*)d_in[2];
  const float* W_ih = (const float*)d_in[4];
  const float* W_hh = (const float*)d_in[5];
  const float* b_ih = (const float*)d_in[6];
  const float* b_hh = (const float*)d_in[7];
  float* out = (float*)d_out;

  char* ws = (char*)d_ws;
  size_t off = 0;
  auto alloc = [&](size_t bytes) {
    void* p = ws + off;
    off += (bytes + 255) & ~(size_t)255;
    return p;
  };
  ushort* Abuf  = (ushort*)alloc((size_t)BATCH_N * LDA_A * 2);  // 50.3 MB
  ushort* Qb    = (ushort*)alloc((size_t)BATCH_N * D_IN * 2);   // 16.8 MB
  ushort* We    = (ushort*)alloc((size_t)GN * 512 * 2);         // 1.05 MB
  ushort* Wo    = (ushort*)alloc((size_t)GN * 512 * 2);         // 1.05 MB
  ushort* Wq    = (ushort*)alloc((size_t)GN * 256 * 2);         // 0.52 MB
  float4* biasp = (float4*)alloc((size_t)NUNIT * 16);
  ushort* Shi   = (ushort*)alloc((size_t)NSUP * D_IN * 2);
  ushort* Slo   = (ushort*)alloc((size_t)NSUP * D_IN * 2);
  ushort* STb   = (ushort*)alloc((size_t)D_IN * NSUP * 2);
  float*  cbuf  = (float*) alloc((size_t)BATCH_N * NUNIT * 4);  // 33.6 MB
  ushort* Hlo   = (ushort*)alloc((size_t)BATCH_N * D_IN * 2);   // 16.8 MB
  uint2*  Gq    = (uint2*) alloc((size_t)BATCH_N * NUNIT * 8);  // 67.1 MB
  ushort* attn  = (ushort*)alloc((size_t)BATCH_N * NSUP * 2);   // 33.6 MB
  if (off > ws_size) return;  // total ~222 MB; >=255 MB proven available

  hipLaunchKernelGGL(k_build, dim3((GN * 512) / 256), dim3(256), 0, stream,
                     W_ih, W_hh, b_ih, b_hh, support_mean,
                     We, Wo, Wq, biasp, Shi, Slo, STb);
  hipLaunchKernelGGL(k_initq, dim3((BATCH_N * D_IN) / 256), dim3(256), 0, stream,
                     query_mean, Qb);

  // Gq = q@Wq^T + b (shared by all steps) + step-0 pointwise -> h_a, c.
  hipLaunchKernelGGL(gemm_gq_fused,
                     dim3((BATCH_N / 128) * (GN / 128)), dim3(256), 0, stream,
                     Qb, Wq, biasp, Gq, cbuf, query_mean, Abuf + 0, Hlo);

  for (int s = 0; s < 4; s++) {
    const int hoff = (s & 1) * 512;   // h slot of step s: even->h_a(0), odd->h_b(512)
    hipLaunchKernelGGL(gemm_scores,
                       dim3((BATCH_N / 128) * (NSUP / 128)), dim3(256), 0, stream,
                       Abuf + hoff, Hlo, Shi, Slo, out);
    if (s < 3) {
      hipLaunchKernelGGL(k_softmax, dim3(BATCH_N / 4), dim3(256), 0, stream, out, attn);
      hipLaunchKernelGGL(gemm_pv,
                         dim3((BATCH_N / 128) * (D_IN / 128)), dim3(256), 0, stream,
                         attn, STb, Abuf + 256);
      // gates for step s+1: window [h|r] (cols 0:512, We) except step 2 reads
      // [r|h_b] (cols 256:768, Wo). h-out goes to the other slot.
      const int aoff = ((s + 1) == 2) ? 256 : 0;
      const ushort* Wnext = ((s + 1) == 2) ? Wo : We;
      hipLaunchKernelGGL(gemm_gates_fused,
                         dim3((BATCH_N / 128) * (GN / 128)), dim3(256), 0, stream,
                         Abuf + aoff, Wnext, Gq, cbuf, query_mean,
                         Abuf + ((s + 1) & 1) * 512, Hlo);
    }
  }
}

// Round 9
// 553.672 us; speedup vs baseline: 1.2980x; 1.2980x over previous
//
#include <hip/hip_runtime.h>

typedef unsigned int uint;
typedef unsigned short ushort;
typedef __attribute__((ext_vector_type(8))) short bhalf8;
typedef __attribute__((ext_vector_type(4))) float floatx4;

#define D_IN 256
#define NUNIT 256     // live hidden units (256:512 dead: h_new[:,256:] never read)
#define GN 1024       // gates N = 4 gates x 256 units
#define NSUP 512
#define BATCH_N 32768
#define LDA_A 768     // A_cat: [h_a(0:256) | r(256:512) | h_b(512:768)]

__device__ __forceinline__ ushort f2b(float f){
  union { float f; uint u; } x; x.f = f;
  uint r = (x.u + 0x7fffu + ((x.u >> 16) & 1u)) >> 16;
  return (ushort)r;
}
__device__ __forceinline__ float b2f(ushort u){
  union { uint u; float f; } x; x.u = ((uint)u) << 16;
  return x.f;
}
__device__ __forceinline__ float sigmf(float x){ return 1.0f / (1.0f + __expf(-x)); }
__device__ __forceinline__ float tanhfast(float x){ return 1.0f - 2.0f / (1.0f + __expf(2.0f * x)); }

// ---------------------------------------------------------------------------
// global->LDS staging of a 128x64 bf16 tile, SOURCE PRE-SWIZZLE (m173):
// LDS linear; lane fetches global octet (lane&7)^(lane>>3) so
// LDS[R][o] = G[R][o ^ (R&7)]; reads apply the same XOR (frag_ld).
// Verified round 5: bank conflicts 3.8e7 -> 0. 4-wave and 8-wave variants.
// ---------------------------------------------------------------------------
__device__ __forceinline__ void stage_swz4(
    ushort* lds, const ushort* __restrict__ g, int ld, int row0, int k0,
    int wave, int lane)
{
  const int rsub = lane >> 3;
  const int oct  = (lane & 7) ^ rsub;
  #pragma unroll
  for (int q = 0; q < 4; q++) {
    const ushort* gp = g + (long)(row0 + wave * 32 + q * 8 + rsub) * ld
                         + k0 + (oct << 3);
    ushort* lp = lds + (wave * 32 + q * 8) * 64;
    __builtin_amdgcn_global_load_lds(
        (const __attribute__((address_space(1))) void*)gp,
        (__attribute__((address_space(3))) void*)lp, 16, 0, 0);
  }
}

__device__ __forceinline__ void stage_swz8(
    ushort* lds, const ushort* __restrict__ g, int ld, int row0, int k0,
    int wave, int lane)
{
  const int rsub = lane >> 3;
  const int oct  = (lane & 7) ^ rsub;
  #pragma unroll
  for (int q = 0; q < 2; q++) {
    const ushort* gp = g + (long)(row0 + wave * 16 + q * 8 + rsub) * ld
                         + k0 + (oct << 3);
    ushort* lp = lds + (wave * 16 + q * 8) * 64;
    __builtin_amdgcn_global_load_lds(
        (const __attribute__((address_space(1))) void*)gp,
        (__attribute__((address_space(3))) void*)lp, 16, 0, 0);
  }
}

__device__ __forceinline__ bhalf8 frag_ld(const ushort* lds, int R, int O, int sx)
{
  return *reinterpret_cast<const bhalf8*>(&lds[R * 64 + (((O ^ sx) & 7) << 3)]);
}

// ---------------------------------------------------------------------------
// Gq = q @ Wq^T + bias (K=256, N=1024 permuted) -> packed bf16 uint2 {i|f,g|o}.
// Epilogue also runs step-0 pointwise (fp32 query!). 512 thr / 8 waves, 32x64.
// ---------------------------------------------------------------------------
__global__ __launch_bounds__(512) void gemm_gq_fused(
    const ushort* __restrict__ Qb,     // [32768,256] bf16 (GEMM A operand)
    const ushort* __restrict__ Wq,     // permuted [1024,256]
    const float4* __restrict__ biasp,  // [256] (b_i,b_f,b_g,b_o)
    uint2* __restrict__ Gq,            // [32768*256]
    float* __restrict__ cbuf,          // [32768,256]
    const float* __restrict__ query,   // fp32 (epilogue h = q + o*tanh(c))
    ushort* __restrict__ Hhi,          // Abuf + 0 (stride LDA_A)
    ushort* __restrict__ Hlo)          // [32768,256]
{
  __shared__ ushort SM[2][8192];       // As / Bs, 32 KB total

  const int tid  = threadIdx.x;
  const int lane = tid & 63;
  const int wave = tid >> 6;           // 0..7
  const int wrow = (wave >> 1) * 32;
  const int wcol = (wave & 1) * 64;
  const int wg = (blockIdx.x & 7) * (gridDim.x >> 3) + (blockIdx.x >> 3);
  const int bm = wg >> 3;              // GN/128 = 8 col-blocks
  const int bn = wg & 7;
  const int rowA0 = bm * 128;
  const int colB0 = bn * 128;

  floatx4 acc[2][4];
  #pragma unroll
  for (int m = 0; m < 2; m++)
    #pragma unroll
    for (int n = 0; n < 4; n++)
      acc[m][n] = (floatx4){0.f, 0.f, 0.f, 0.f};

  const int lr = lane & 15;
  const int lg = lane >> 4;
  const int sx = lane & 7;

  for (int k0 = 0; k0 < 256; k0 += 64) {
    stage_swz8(SM[0], Qb, 256, rowA0, k0, wave, lane);
    stage_swz8(SM[1], Wq, 256, colB0, k0, wave, lane);
    __syncthreads();
    #pragma unroll
    for (int ks = 0; ks < 2; ks++) {
      bhalf8 af[2], bfr[4];
      #pragma unroll
      for (int m = 0; m < 2; m++)
        af[m] = frag_ld(SM[0], wrow + m * 16 + lr, ks * 4 + lg, sx);
      #pragma unroll
      for (int n = 0; n < 4; n++)
        bfr[n] = frag_ld(SM[1], wcol + n * 16 + lr, ks * 4 + lg, sx);
      #pragma unroll
      for (int m = 0; m < 2; m++)
        #pragma unroll
        for (int n = 0; n < 4; n++)
          acc[m][n] = __builtin_amdgcn_mfma_f32_16x16x32_bf16(af[m], bfr[n], acc[m][n], 0, 0, 0);
    }
    __syncthreads();
  }

  // ---- epilogue: Gq direct (coalesced uint2), h/lo/c via LDS transpose ----
  ushort* ehi = (ushort*)SM[0];                 // [128][32] = 8 KB
  ushort* elo = ehi + 128 * 32;                 // 8 KB
  float*  ec  = (float*)SM[1];                  // [128][32] f32 = 16 KB

  const int u_loc = (wave & 1) * 16 + lr;       // 0..31
  const int u     = bn * 32 + u_loc;
  const float4 b4 = biasp[u];
  #pragma unroll
  for (int m = 0; m < 2; m++) {
    #pragma unroll
    for (int rr = 0; rr < 4; rr++) {
      const int  rloc = wrow + m * 16 + lg * 4 + rr;
      const long row  = rowA0 + rloc;
      float pi = acc[m][0][rr] + b4.x;
      float pf = acc[m][1][rr] + b4.y;
      float pg = acc[m][2][rr] + b4.z;
      float po = acc[m][3][rr] + b4.w;
      uint2 pk;
      pk.x = (uint)f2b(pi) | ((uint)f2b(pf) << 16);
      pk.y = (uint)f2b(pg) | ((uint)f2b(po) << 16);
      Gq[row * NUNIT + u] = pk;
      float cn = sigmf(pi) * tanhfast(pg);
      ec[rloc * 32 + u_loc] = cn;
      float h = query[row * D_IN + u] + sigmf(po) * tanhfast(cn);
      ushort hh = f2b(h);
      ehi[rloc * 32 + u_loc] = hh;
      elo[rloc * 32 + u_loc] = f2b(h - b2f(hh));
    }
  }
  __syncthreads();
  const int u0 = bn * 32;
  {                                             // hi/lo: [128][32]u16 = 512 uint4
    int row = tid >> 2, part = tid & 3;
    *(uint4*)(Hhi + (long)(rowA0 + row) * LDA_A + u0 + part * 8) = ((const uint4*)ehi)[tid];
    *(uint4*)(Hlo + (long)(rowA0 + row) * D_IN + u0 + part * 8) = ((const uint4*)elo)[tid];
  }
  #pragma unroll
  for (int i = tid; i < 1024; i += 512) {       // c: [128][32]f32 = 1024 uint4
    int row = i >> 3, part = i & 7;
    *(uint4*)(cbuf + (long)(rowA0 + row) * NUNIT + u0 + part * 4) = ((const uint4*)ec)[i];
  }
}

// ---------------------------------------------------------------------------
// Steps 1-3: gates = A[:, aoff:aoff+512] @ Whh'^T (K=512, N=1024) + Gq;
// fused LSTM pointwise (fp32 query). 512 thr / 8 waves, 32 KB LDS.
// ---------------------------------------------------------------------------
__global__ __launch_bounds__(512) void gemm_gates_fused(
    const ushort* __restrict__ A,      // Abuf + aoff (lda LDA_A)
    const ushort* __restrict__ W,      // permuted [1024,512]
    const uint2* __restrict__ Gq,      // packed q-contribution (incl bias)
    float* __restrict__ cbuf,
    const float* __restrict__ query,   // fp32
    ushort* __restrict__ Hhi,          // A_cat h-out slot (stride LDA_A)
    ushort* __restrict__ Hlo)
{
  __shared__ ushort SM[2][8192];

  const int tid  = threadIdx.x;
  const int lane = tid & 63;
  const int wave = tid >> 6;
  const int wrow = (wave >> 1) * 32;
  const int wcol = (wave & 1) * 64;
  const int wg = (blockIdx.x & 7) * (gridDim.x >> 3) + (blockIdx.x >> 3);
  const int bm = wg >> 3;
  const int bn = wg & 7;
  const int rowA0 = bm * 128;
  const int colB0 = bn * 128;

  floatx4 acc[2][4];
  #pragma unroll
  for (int m = 0; m < 2; m++)
    #pragma unroll
    for (int n = 0; n < 4; n++)
      acc[m][n] = (floatx4){0.f, 0.f, 0.f, 0.f};

  const int lr = lane & 15;
  const int lg = lane >> 4;
  const int sx = lane & 7;

  for (int k0 = 0; k0 < 512; k0 += 64) {
    stage_swz8(SM[0], A, LDA_A, rowA0, k0, wave, lane);
    stage_swz8(SM[1], W, 512,   colB0, k0, wave, lane);
    __syncthreads();
    #pragma unroll
    for (int ks = 0; ks < 2; ks++) {
      bhalf8 af[2], bfr[4];
      #pragma unroll
      for (int m = 0; m < 2; m++)
        af[m] = frag_ld(SM[0], wrow + m * 16 + lr, ks * 4 + lg, sx);
      #pragma unroll
      for (int n = 0; n < 4; n++)
        bfr[n] = frag_ld(SM[1], wcol + n * 16 + lr, ks * 4 + lg, sx);
      #pragma unroll
      for (int m = 0; m < 2; m++)
        #pragma unroll
        for (int n = 0; n < 4; n++)
          acc[m][n] = __builtin_amdgcn_mfma_f32_16x16x32_bf16(af[m], bfr[n], acc[m][n], 0, 0, 0);
    }
    __syncthreads();
  }

  // ---- epilogue: pointwise -> LDS transpose -> coalesced writeout ----
  ushort* ehi = (ushort*)SM[0];
  ushort* elo = ehi + 128 * 32;
  float*  ec  = (float*)SM[1];

  const int u_loc = (wave & 1) * 16 + lr;
  const int u     = bn * 32 + u_loc;
  #pragma unroll
  for (int m = 0; m < 2; m++) {
    #pragma unroll
    for (int rr = 0; rr < 4; rr++) {
      const int  rloc = wrow + m * 16 + lg * 4 + rr;
      const long row  = rowA0 + rloc;
      uint2 pk = Gq[row * NUNIT + u];
      float pi = acc[m][0][rr] + b2f((ushort)(pk.x & 0xffff));
      float pf = acc[m][1][rr] + b2f((ushort)(pk.x >> 16));
      float pg = acc[m][2][rr] + b2f((ushort)(pk.y & 0xffff));
      float po = acc[m][3][rr] + b2f((ushort)(pk.y >> 16));
      float cn = sigmf(pf) * cbuf[row * NUNIT + u] + sigmf(pi) * tanhfast(pg);
      ec[rloc * 32 + u_loc] = cn;
      float h = query[row * D_IN + u] + sigmf(po) * tanhfast(cn);
      ushort hh = f2b(h);
      ehi[rloc * 32 + u_loc] = hh;
      elo[rloc * 32 + u_loc] = f2b(h - b2f(hh));
    }
  }
  __syncthreads();
  const int u0 = bn * 32;
  {
    int row = tid >> 2, part = tid & 3;
    *(uint4*)(Hhi + (long)(rowA0 + row) * LDA_A + u0 + part * 8) = ((const uint4*)ehi)[tid];
    *(uint4*)(Hlo + (long)(rowA0 + row) * D_IN + u0 + part * 8) = ((const uint4*)elo)[tid];
  }
  #pragma unroll
  for (int i = tid; i < 1024; i += 512) {
    int row = i >> 3, part = i & 7;
    *(uint4*)(cbuf + (long)(rowA0 + row) * NUNIT + u0 + part * 4) = ((const uint4*)ec)[i];
  }
}

// ---------------------------------------------------------------------------
// Split-precision scores GEMM: C = (Ahi+Alo)@(Bhi+Blo)^T, lo*lo dropped.
// Ahi from A_cat h-slot (lda 768). K=256. C fp32 [32768,512]. (round-6 form)
// ---------------------------------------------------------------------------
__global__ __launch_bounds__(256) void gemm_scores(
    const ushort* __restrict__ Ahi,
    const ushort* __restrict__ Alo,
    const ushort* __restrict__ Bhi, const ushort* __restrict__ Blo,
    float* __restrict__ C)
{
  __shared__ ushort AsH[128 * 64];
  __shared__ ushort AsL[128 * 64];
  __shared__ ushort BsH[128 * 64];
  __shared__ ushort BsL[128 * 64];

  const int tid  = threadIdx.x;
  const int lane = tid & 63;
  const int wave = tid >> 6;
  const int wr = (wave >> 1) * 64;
  const int wc = (wave & 1) * 64;
  const int wg = (blockIdx.x & 7) * (gridDim.x >> 3) + (blockIdx.x >> 3);
  const int bm = wg >> 2;      // NSUP/128 = 4
  const int bn = wg & 3;
  const int rowA0 = bm * 128;
  const int rowB0 = bn * 128;

  floatx4 acc[4][4];
  #pragma unroll
  for (int m = 0; m < 4; m++)
    #pragma unroll
    for (int n = 0; n < 4; n++)
      acc[m][n] = (floatx4){0.f, 0.f, 0.f, 0.f};

  const int lr = lane & 15;
  const int lg = lane >> 4;
  const int sx = lane & 7;

  for (int k0 = 0; k0 < D_IN; k0 += 64) {
    stage_swz4(AsH, Ahi, LDA_A, rowA0, k0, wave, lane);
    stage_swz4(AsL, Alo, D_IN,  rowA0, k0, wave, lane);
    stage_swz4(BsH, Bhi, D_IN,  rowB0, k0, wave, lane);
    stage_swz4(BsL, Blo, D_IN,  rowB0, k0, wave, lane);
    __syncthreads();
    #pragma unroll
    for (int ks = 0; ks < 2; ks++) {
      bhalf8 afh[4], afl[4], bfh[4], bfl[4];
      #pragma unroll
      for (int m = 0; m < 4; m++) {
        afh[m] = frag_ld(AsH, wr + m * 16 + lr, ks * 4 + lg, sx);
        afl[m] = frag_ld(AsL, wr + m * 16 + lr, ks * 4 + lg, sx);
      }
      #pragma unroll
      for (int n = 0; n < 4; n++) {
        bfh[n] = frag_ld(BsH, wc + n * 16 + lr, ks * 4 + lg, sx);
        bfl[n] = frag_ld(BsL, wc + n * 16 + lr, ks * 4 + lg, sx);
      }
      #pragma unroll
      for (int m = 0; m < 4; m++)
        #pragma unroll
        for (int n = 0; n < 4; n++) {
          acc[m][n] = __builtin_amdgcn_mfma_f32_16x16x32_bf16(afl[m], bfh[n], acc[m][n], 0, 0, 0);
          acc[m][n] = __builtin_amdgcn_mfma_f32_16x16x32_bf16(afh[m], bfl[n], acc[m][n], 0, 0, 0);
          acc[m][n] = __builtin_amdgcn_mfma_f32_16x16x32_bf16(afh[m], bfh[n], acc[m][n], 0, 0, 0);
        }
    }
    __syncthreads();
  }

  #pragma unroll
  for (int m = 0; m < 4; m++)
    #pragma unroll
    for (int n = 0; n < 4; n++)
      #pragma unroll
      for (int r = 0; r < 4; r++) {
        int row = rowA0 + wr + m * 16 + lg * 4 + r;
        int col = rowB0 + wc + n * 16 + lr;
        C[(long)row * NSUP + col] = acc[m][n][r];
      }
}

// ---------------------------------------------------------------------------
// PV GEMM: r = attn @ STb^T (K=512), bf16 out into A_cat r-slot (ldc 768).
// Single-buffered, 4 waves; LDS-transposed coalesced writeout.
// ---------------------------------------------------------------------------
__global__ __launch_bounds__(256) void gemm_pv(
    const ushort* __restrict__ A,      // attn [32768,512]
    const ushort* __restrict__ B,      // STb [256,512]
    ushort* __restrict__ Cv)           // Abuf + 256
{
  __shared__ ushort SM[2][8192];

  const int tid  = threadIdx.x;
  const int lane = tid & 63;
  const int wave = tid >> 6;
  const int wr = (wave >> 1) * 64;
  const int wc = (wave & 1) * 64;
  const int wg = (blockIdx.x & 7) * (gridDim.x >> 3) + (blockIdx.x >> 3);
  const int bm = wg >> 1;             // D_IN/128 = 2
  const int bn = wg & 1;
  const int rowA0 = bm * 128;
  const int rowB0 = bn * 128;

  floatx4 acc[4][4];
  #pragma unroll
  for (int m = 0; m < 4; m++)
    #pragma unroll
    for (int n = 0; n < 4; n++)
      acc[m][n] = (floatx4){0.f, 0.f, 0.f, 0.f};

  const int lr = lane & 15;
  const int lg = lane >> 4;
  const int sx = lane & 7;

  for (int k0 = 0; k0 < NSUP; k0 += 64) {
    stage_swz4(SM[0], A, NSUP, rowA0, k0, wave, lane);
    stage_swz4(SM[1], B, NSUP, rowB0, k0, wave, lane);
    __syncthreads();
    #pragma unroll
    for (int ks = 0; ks < 2; ks++) {
      bhalf8 af[4], bfr[4];
      #pragma unroll
      for (int m = 0; m < 4; m++)
        af[m] = frag_ld(SM[0], wr + m * 16 + lr, ks * 4 + lg, sx);
      #pragma unroll
      for (int n = 0; n < 4; n++)
        bfr[n] = frag_ld(SM[1], wc + n * 16 + lr, ks * 4 + lg, sx);
      #pragma unroll
      for (int m = 0; m < 4; m++)
        #pragma unroll
        for (int n = 0; n < 4; n++)
          acc[m][n] = __builtin_amdgcn_mfma_f32_16x16x32_bf16(af[m], bfr[n], acc[m][n], 0, 0, 0);
    }
    __syncthreads();
  }

  // epilogue: r tile [128][128] bf16 via LDS (32 KB = SM), coalesced writeout
  ushort* elr = (ushort*)SM;
  #pragma unroll
  for (int m = 0; m < 4; m++)
    #pragma unroll
    for (int n = 0; n < 4; n++)
      #pragma unroll
      for (int r = 0; r < 4; r++) {
        int rloc = wr + m * 16 + lg * 4 + r;
        int cloc = wc + n * 16 + lr;
        elr[rloc * 128 + cloc] = f2b(acc[m][n][r]);
      }
  __syncthreads();
  for (int i = tid; i < 2048; i += 256) {
    int row = i >> 4, part = i & 15;
    *(uint4*)(Cv + (long)(rowA0 + row) * LDA_A + rowB0 + part * 8) = ((const uint4*)elr)[i];
  }
}

// ---------------------------------------------------------------------------
// Build permuted live-unit weights + bias + S hi/lo + S^T. (unchanged)
// Permuted col c: unit = (c>>6)*16 + (c&15), gate = (c>>4)&3.
// ---------------------------------------------------------------------------
__global__ __launch_bounds__(256) void k_build(
    const float* __restrict__ Wih, const float* __restrict__ Whh,
    const float* __restrict__ bih, const float* __restrict__ bhh,
    const float* __restrict__ S,
    ushort* __restrict__ We, ushort* __restrict__ Wo, ushort* __restrict__ Wq,
    float4* __restrict__ biasp,
    ushort* __restrict__ Shi, ushort* __restrict__ Slo,
    ushort* __restrict__ STb)
{
  int t = blockIdx.x * 256 + threadIdx.x;
  if (t < GN * 512) {
    int c = t >> 9, k = t & 511;
    int unit = (c >> 6) * 16 + (c & 15);
    int gate = (c >> 4) & 3;
    long srow = (long)(gate * 512 + unit);
    We[(long)c * 512 + k] = f2b(Whh[srow * 512 + k]);
    int ko = (k < 256) ? (256 + k) : (k - 256);
    Wo[(long)c * 512 + k] = f2b(Whh[srow * 512 + ko]);
    if (k < 256) Wq[(long)c * 256 + k] = f2b(Wih[srow * 256 + k]);
  }
  if (t < NUNIT) {
    biasp[t] = make_float4(bih[t] + bhh[t],
                           bih[512 + t] + bhh[512 + t],
                           bih[1024 + t] + bhh[1024 + t],
                           bih[1536 + t] + bhh[1536 + t]);
  }
  if (t < NSUP * D_IN) {
    float v = S[t];
    ushort hv = f2b(v);
    Shi[t] = hv;
    Slo[t] = f2b(v - b2f(hv));
    int s = t >> 8, d = t & 255;
    STb[(long)d * NSUP + s] = hv;
  }
}

// bf16 copy of query (GEMM operand only; epilogues use fp32 query).
__global__ __launch_bounds__(256) void k_initq(
    const float* __restrict__ query, ushort* __restrict__ Qb)
{
  long t = (long)blockIdx.x * 256 + threadIdx.x;
  Qb[t] = f2b(query[t]);
}

// Row softmax over 512 cols, fp32 in, bf16 out. 1 wave / row. (unchanged)
__global__ __launch_bounds__(256) void k_softmax(
    const float* __restrict__ sc, ushort* __restrict__ attn)
{
  int row  = blockIdx.x * 4 + (threadIdx.x >> 6);
  int lane = threadIdx.x & 63;
  const float4* sp = reinterpret_cast<const float4*>(sc + (long)row * NSUP);
  float4 v0 = sp[lane];
  float4 v1 = sp[64 + lane];
  float m = fmaxf(fmaxf(fmaxf(v0.x, v0.y), fmaxf(v0.z, v0.w)),
                  fmaxf(fmaxf(v1.x, v1.y), fmaxf(v1.z, v1.w)));
  #pragma unroll
  for (int off = 32; off >= 1; off >>= 1) m = fmaxf(m, __shfl_xor(m, off));
  float e0 = __expf(v0.x - m), e1 = __expf(v0.y - m), e2 = __expf(v0.z - m), e3 = __expf(v0.w - m);
  float e4 = __expf(v1.x - m), e5 = __expf(v1.y - m), e6 = __expf(v1.z - m), e7 = __expf(v1.w - m);
  float s = e0 + e1 + e2 + e3 + e4 + e5 + e6 + e7;
  #pragma unroll
  for (int off = 32; off >= 1; off >>= 1) s += __shfl_xor(s, off);
  float inv = 1.0f / s;
  uint2 p0, p1;
  p0.x = (uint)f2b(e0 * inv) | ((uint)f2b(e1 * inv) << 16);
  p0.y = (uint)f2b(e2 * inv) | ((uint)f2b(e3 * inv) << 16);
  p1.x = (uint)f2b(e4 * inv) | ((uint)f2b(e5 * inv) << 16);
  p1.y = (uint)f2b(e6 * inv) | ((uint)f2b(e7 * inv) << 16);
  uint2* ap = reinterpret_cast<uint2*>(attn + (long)row * NSUP);
  ap[lane] = p0;
  ap[64 + lane] = p1;
}

// ---------------------------------------------------------------------------
extern "C" void kernel_launch(void* const* d_in, const int* in_sizes, int n_in,
                              void* d_out, int out_size, void* d_ws, size_t ws_size,
                              hipStream_t stream)
{
  const float* support_mean = (const float*)d_in[0];
  const float* query_mean   = (const float*)d_in[2];
  const float* W_ih = (const float*)d_in[4];
  const float* W_hh = (const float*)d_in[5];
  const float* b_ih = (const float*)d_in[6];
  const float* b_hh = (const float*)d_in[7];
  float* out = (float*)d_out;

  char* ws = (char*)d_ws;
  size_t off = 0;
  auto alloc = [&](size_t bytes) {
    void* p = ws + off;
    off += (bytes + 255) & ~(size_t)255;
    return p;
  };
  ushort* Abuf  = (ushort*)alloc((size_t)BATCH_N * LDA_A * 2);  // 50.3 MB
  ushort* Qb    = (ushort*)alloc((size_t)BATCH_N * D_IN * 2);   // 16.8 MB
  ushort* We    = (ushort*)alloc((size_t)GN * 512 * 2);         // 1.05 MB
  ushort* Wo    = (ushort*)alloc((size_t)GN * 512 * 2);         // 1.05 MB
  ushort* Wq    = (ushort*)alloc((size_t)GN * 256 * 2);         // 0.52 MB
  float4* biasp = (float4*)alloc((size_t)NUNIT * 16);
  ushort* Shi   = (ushort*)alloc((size_t)NSUP * D_IN * 2);
  ushort* Slo   = (ushort*)alloc((size_t)NSUP * D_IN * 2);
  ushort* STb   = (ushort*)alloc((size_t)D_IN * NSUP * 2);
  float*  cbuf  = (float*) alloc((size_t)BATCH_N * NUNIT * 4);  // 33.6 MB
  ushort* Hlo   = (ushort*)alloc((size_t)BATCH_N * D_IN * 2);   // 16.8 MB
  uint2*  Gq    = (uint2*) alloc((size_t)BATCH_N * NUNIT * 8);  // 67.1 MB
  ushort* attn  = (ushort*)alloc((size_t)BATCH_N * NSUP * 2);   // 33.6 MB
  if (off > ws_size) return;  // total ~222 MB; >=255 MB proven available

  hipLaunchKernelGGL(k_build, dim3((GN * 512) / 256), dim3(256), 0, stream,
                     W_ih, W_hh, b_ih, b_hh, support_mean,
                     We, Wo, Wq, biasp, Shi, Slo, STb);
  hipLaunchKernelGGL(k_initq, dim3((BATCH_N * D_IN) / 256), dim3(256), 0, stream,
                     query_mean, Qb);

  // Gq = q@Wq^T + b (shared by all steps) + step-0 pointwise -> h_a, c.
  hipLaunchKernelGGL(gemm_gq_fused,
                     dim3((BATCH_N / 128) * (GN / 128)), dim3(512), 0, stream,
                     Qb, Wq, biasp, Gq, cbuf, query_mean, Abuf + 0, Hlo);

  for (int s = 0; s < 4; s++) {
    const int hoff = (s & 1) * 512;   // h slot of step s: even->h_a(0), odd->h_b(512)
    hipLaunchKernelGGL(gemm_scores,
                       dim3((BATCH_N / 128) * (NSUP / 128)), dim3(256), 0, stream,
                       Abuf + hoff, Hlo, Shi, Slo, out);
    if (s < 3) {
      hipLaunchKernelGGL(k_softmax, dim3(BATCH_N / 4), dim3(256), 0, stream, out, attn);
      hipLaunchKernelGGL(gemm_pv,
                         dim3((BATCH_N / 128) * (D_IN / 128)), dim3(256), 0, stream,
                         attn, STb, Abuf + 256);
      // gates for step s+1: window [h|r] (cols 0:512, We) except step 2 reads
      // [r|h_b] (cols 256:768, Wo). h-out goes to the other slot.
      const int aoff = ((s + 1) == 2) ? 256 : 0;
      const ushort* Wnext = ((s + 1) == 2) ? Wo : We;
      hipLaunchKernelGGL(gemm_gates_fused,
                         dim3((BATCH_N / 128) * (GN / 128)), dim3(512), 0, stream,
                         Abuf + aoff, Wnext, Gq, cbuf, query_mean,
                         Abuf + ((s + 1) & 1) * 512, Hlo);
    }
  }
}